// Round 7
// baseline (588.293 us; speedup 1.0000x reference)
//
#include <hip/hip_runtime.h>
#include <hip/hip_bf16.h>

#define N_ROWS 100000
#define P_DIM 512
#define D_DIM 256
#define TAU12 2.0e-2f
#define TAU13 1.5e-2f

typedef __attribute__((ext_vector_type(4))) float f32x4;
typedef __attribute__((ext_vector_type(8))) short s16x8;

__device__ __forceinline__ unsigned bf16_rne_bits(float x) {
  unsigned u = __float_as_uint(x);
  return (u + 0x7fffu + ((u >> 16) & 1u)) >> 16;
}

__device__ __forceinline__ void gll16(const void* gsrc, void* ldst) {
  __builtin_amdgcn_global_load_lds(
      (const __attribute__((address_space(1))) unsigned char*)gsrc,
      (__attribute__((address_space(3))) unsigned char*)ldst, 16, 0, 0);
}

// ---------------- prep ----------------
// blocks 0..63:  pa_swz — patch bf16(hi), 8 tiles of [64 p][256 d], rows
//                XOR-swizzled (byte ^= (row&15)<<4): main stages LINEARLY
//                (global_load_lds) and ds_reads are conflict-free.
// blocks 64..127: p_T_perm — patch bf16 transposed [d][p], GEMM2 k-perm
//                baked in; unit u = ((t2*16+kc)*16+cc)*4+g, d = t2*16+cc,
//                elem j <-> p = 32kc + 16*(j>>2) + 4g + (j&3).
__global__ void prep_kernel(const float* __restrict__ patch,
                            short* __restrict__ pa_swz,
                            short* __restrict__ p_T_perm) {
  int b = blockIdx.x, t = threadIdx.x;
  if (b < 64) {
    int u = b * 256 + t;                  // 16384 16B-units total
    int bt = u >> 11;                     // 2048 units per 32KB tile
    int Lb = (u & 2047) * 16;             // dest byte within tile
    int r  = Lb >> 9;                     // p-row in tile (512B rows)
    int srcb = Lb ^ ((r & 15) << 4);      // involutive swizzle
    int p = bt * 64 + r;
    int d0 = (srcb & 511) >> 1;
    s16x8 v;
#pragma unroll
    for (int q = 0; q < 8; ++q)
      v[q] = (short)bf16_rne_bits(patch[(size_t)p * D_DIM + d0 + q]);
    *(s16x8*)(pa_swz + (size_t)u * 8) = v;
  } else {
    int u = (b - 64) * 256 + t;           // 16384 units
    int g = u & 3, cc = (u >> 2) & 15, kc = (u >> 6) & 15, t2 = u >> 10;
    int d = t2 * 16 + cc;
    s16x8 v;
#pragma unroll
    for (int j = 0; j < 8; ++j) {
      int p = 32 * kc + 16 * (j >> 2) + 4 * g + (j & 3);
      v[j] = (short)bf16_rne_bits(patch[(size_t)p * D_DIM + d]);
    }
    *(s16x8*)(p_T_perm + (size_t)u * 8) = v;
  }
}

// finalize one 256-p half: exp + online top-3 + immediate bf16 store of
// unnormalized probs into the group's pf region (out_rec memory, reused).
#define FINALIZE_STORE(H) do {                                        \
  _Pragma("unroll")                                                   \
  for (int kc = 0; kc < 8; ++kc) {                                    \
    s16x8 f;                                                          \
    _Pragma("unroll")                                                 \
    for (int j = 0; j < 8; ++j) {                                     \
      int tl = 2 * kc + (j >> 2);                                     \
      float v = acc[tl][j & 3];                                       \
      int col = (H) * 256 + 16 * tl + 4 * g + (j & 3);                \
      float e = __expf(v);                                            \
      s += e;                                                         \
      f[j] = (short)bf16_rne_bits(e);                                 \
      bool g1 = v > m1, g2 = v > m2, g3 = v > m3;                     \
      m3 = g2 ? m2 : (g3 ? v : m3);                                   \
      i2 = g1 ? i1 : (g2 ? col : i2);                                 \
      m2 = g1 ? m1 : (g2 ? v : m2);                                   \
      i1 = g1 ? col : i1;                                             \
      m1 = g1 ? v : m1;                                               \
    }                                                                 \
    if (ok)                                                           \
      *(s16x8*)(pfout + ((size_t)G * 1024 + (H) * 512 + kc * 64 + lane) * 8) = f; \
  }                                                                   \
} while (0)

// stage 16KB tile T into LDS buffer BUF via global_load_lds (linear dest)
#define STAGE(BUF, T) do {                                            \
  const char* gs_ = (const char*)pa_swz + (size_t)(T) * 16384         \
                    + (size_t)w * 4096 + (size_t)lane * 16;           \
  char* ls_ = &B1[BUF][w * 4096];                                     \
  _Pragma("unroll")                                                   \
  for (int i_ = 0; i_ < 4; ++i_)                                      \
    gll16(gs_ + i_ * 1024, ls_ + i_ * 1024);                          \
} while (0)

// ---------------- gemm1: logits + softmax + argmax + one-hot + pf ----------
// 4 waves/block, 16 node-rows per wave (N_ROWS % 16 == 0 -> whole groups).
__global__ __launch_bounds__(256, 4)
void gemm1_kernel(const float* __restrict__ node,
                  const short* __restrict__ pa_swz,
                  short* __restrict__ pfout,        // = out_rec region (bf16)
                  float* __restrict__ out_hot,
                  unsigned* __restrict__ suspect,
                  float* __restrict__ invs) {
  __shared__ __align__(16) char B1[2][16384];   // double-buffered patch tile

  const int tid = threadIdx.x;
  const int lane = tid & 63;
  const int w = tid >> 6;
  const int cc = lane & 15, g = lane >> 4;
  const int G = blockIdx.x * 4 + w;             // 16-row group id
  const int myrow = G * 16 + cc;
  const bool ok = (G * 16) < N_ROWS;            // whole group valid or not

  STAGE(0, 0);                                  // tile-0 staging in flight

  // ---- node B-frags (hi only, nontemporal): elem e <-> k = kk*32+8g+e ----
  s16x8 nhi[8];
  {
    const float* nr = node + (size_t)myrow * D_DIM;
#pragma unroll
    for (int kk = 0; kk < 8; ++kk) {
      f32x4 v0, v1;
      if (ok) {
        v0 = __builtin_nontemporal_load((const f32x4*)(nr + kk * 32 + g * 8));
        v1 = __builtin_nontemporal_load((const f32x4*)(nr + kk * 32 + g * 8 + 4));
      } else {
        v0 = (f32x4){0.f, 0.f, 0.f, 0.f};
        v1 = (f32x4){0.f, 0.f, 0.f, 0.f};
      }
#pragma unroll
      for (int e = 0; e < 4; ++e) {
        nhi[kk][e]     = (short)bf16_rne_bits(v0[e]);
        nhi[kk][e + 4] = (short)bf16_rne_bits(v1[e]);
      }
    }
  }
  __syncthreads();                              // tile 0 staged

  f32x4 acc[16];
#pragma unroll
  for (int q = 0; q < 16; ++q) acc[q] = (f32x4){0.f, 0.f, 0.f, 0.f};
  float m1 = -1e30f, m2 = -1e30f, m3 = -1e30f;
  int i1 = 0, i2 = 0;
  float s = 0.f;

  // ---- GEMM1: 16 tiles of [32 p][256 k]; finalize each 256-p half ----
#pragma unroll
  for (int t = 0; t < 16; ++t) {
    if (t < 15) STAGE((t + 1) & 1, t + 1);
    __builtin_amdgcn_s_setprio(1);
#pragma unroll
    for (int pt = 0; pt < 2; ++pt) {
      f32x4 a = acc[(t & 7) * 2 + pt];
#pragma unroll
      for (int kk = 0; kk < 8; ++kk) {
        int r = pt * 16 + cc;
        int ad = ((r << 9) + (kk << 6) + (g << 4)) ^ (cc << 4);
        s16x8 af = *(const s16x8*)(&B1[t & 1][ad]);
        a = __builtin_amdgcn_mfma_f32_16x16x32_bf16(af, nhi[kk], a, 0, 0, 0);
      }
      acc[(t & 7) * 2 + pt] = a;
    }
    __builtin_amdgcn_s_setprio(0);
    if (t == 7) {
      FINALIZE_STORE(0);
#pragma unroll
      for (int q = 0; q < 16; ++q) acc[q] = (f32x4){0.f, 0.f, 0.f, 0.f};
    }
    if (t < 15) __syncthreads();                // staged writes visible
  }
  FINALIZE_STORE(1);

  // ---- merge top-3 across the 4 g-lanes of each row ----
#pragma unroll
  for (int mk = 16; mk <= 32; mk <<= 1) {
    float bm1 = __shfl_xor(m1, mk); int bi1 = __shfl_xor(i1, mk);
    float bm2 = __shfl_xor(m2, mk); int bi2 = __shfl_xor(i2, mk);
    float bm3 = __shfl_xor(m3, mk);
    bool sw = (bm1 > m1) || (bm1 == m1 && bi1 < i1);
    float am1 = sw ? bm1 : m1; int ai1 = sw ? bi1 : i1;
    float am2 = sw ? bm2 : m2; int ai2 = sw ? bi2 : i2;
    float am3 = sw ? bm3 : m3;
    float cm1 = sw ? m1 : bm1; int ci1 = sw ? i1 : bi1;
    float cm2 = sw ? m2 : bm2;
    bool t2b = (cm1 > am2) || (cm1 == am2 && ci1 < ai2);
    m1 = am1; i1 = ai1;
    m2 = t2b ? cm1 : am2; i2 = t2b ? ci1 : ai2;
    m3 = t2b ? fmaxf(am2, cm2) : fmaxf(am3, cm1);
  }
  s += __shfl_xor(s, 16);
  s += __shfl_xor(s, 32);

  if (g == 0 && ok) {
    invs[myrow] = 1.0f / s;
    unsigned codev = 0u;
    if (m1 - m2 < TAU12)
      codev = 0x80000000u | ((m1 - m3 < TAU13) ? 0x40000000u : 0u)
            | ((unsigned)i2 << 9) | (unsigned)i1;
    suspect[myrow] = codev;
  }

  // ---- one-hot write (nontemporal; 4 g-lanes cover 64B per row) ----
  if (ok) {
    float* orow = out_hot + (size_t)myrow * P_DIM;
#pragma unroll
    for (int c2i = 0; c2i < 32; ++c2i) {
      int col = c2i * 16 + g * 4;
      f32x4 z;
      z[0] = (i1 == col + 0) ? 1.f : 0.f;
      z[1] = (i1 == col + 1) ? 1.f : 0.f;
      z[2] = (i1 == col + 2) ? 1.f : 0.f;
      z[3] = (i1 == col + 3) ? 1.f : 0.f;
      __builtin_nontemporal_store(z, (f32x4*)(orow + col));
    }
  }
}

// ---------------- gemm2: out_rec = probs @ patch ----------------------------
// Reads pf (bf16, unnormalized) from the out_rec region and overwrites the
// SAME per-group 16KB region with f32 results (race-free: one block owns it).
__global__ __launch_bounds__(256, 3)
void gemm2_kernel(const short* __restrict__ p_T_perm,
                  const float* __restrict__ invs,
                  float* __restrict__ rec) {
  const int tid = threadIdx.x;
  const int lane = tid & 63;
  const int w = tid >> 6;
  const int cc = lane & 15, g = lane >> 4;
  const int G = blockIdx.x * 4 + w;
  if (G * 16 >= N_ROWS) return;                 // wave-uniform, no barriers
  const int myrow = G * 16 + cc;
  const float inv = invs[myrow];

  const s16x8* pf8 = (const s16x8*)rec;         // alias: pf lives here
  s16x8 pfA[8], pfB[8];
#pragma unroll
  for (int kc = 0; kc < 8; ++kc)
    pfA[kc] = pf8[(size_t)G * 1024 + kc * 64 + lane];
#pragma unroll
  for (int kc = 0; kc < 8; ++kc)
    pfB[kc] = pf8[(size_t)G * 1024 + 512 + kc * 64 + lane];

  const s16x8* pT = (const s16x8*)p_T_perm;
  const int lidx = (cc << 2) + g;
#pragma unroll
  for (int t2 = 0; t2 < 16; ++t2) {
    s16x8 aH[16];
    const int ub = t2 << 10;
#pragma unroll
    for (int kc = 0; kc < 16; ++kc) aH[kc] = pT[ub + (kc << 6) + lidx];
    f32x4 c2 = (f32x4){0.f, 0.f, 0.f, 0.f};
    __builtin_amdgcn_s_setprio(1);
#pragma unroll
    for (int kc = 0; kc < 8; ++kc)
      c2 = __builtin_amdgcn_mfma_f32_16x16x32_bf16(aH[kc], pfA[kc], c2, 0, 0, 0);
#pragma unroll
    for (int kc = 0; kc < 8; ++kc)
      c2 = __builtin_amdgcn_mfma_f32_16x16x32_bf16(aH[kc + 8], pfB[kc], c2, 0, 0, 0);
    __builtin_amdgcn_s_setprio(0);
    c2[0] *= inv; c2[1] *= inv; c2[2] *= inv; c2[3] *= inv;
    __builtin_nontemporal_store(c2, (f32x4*)(rec + (size_t)myrow * D_DIM + 16 * t2 + 4 * g));
  }
}

// ---------------- refine: fp64 check of the 2 candidates (dense scan) ------
__global__ void refine_kernel(const float* __restrict__ node,
                              const float* __restrict__ patch,
                              const unsigned* __restrict__ suspect,
                              float* __restrict__ out_hot) {
  const int lane = threadIdx.x;            // blockDim.x == 64
  const int r0 = blockIdx.x * 64;
  unsigned code = (r0 + lane < N_ROWS) ? suspect[r0 + lane] : 0u;
  unsigned long long mask = __ballot(code != 0u);
  while (mask) {
    int src = __ffsll((long long)mask) - 1;
    mask &= mask - 1;
    unsigned c = __shfl(code, src);
    int row = r0 + src;
    int i1 = (int)(c & 511u), i2 = (int)((c >> 9) & 511u);
    if (!(c & 0x40000000u)) {
      // exact fp64 dots for the two candidates; halves of the wave split them
      int pidx = (lane >= 32) ? i2 : i1;
      int l5 = lane & 31;
      double sd = 0.0;
#pragma unroll
      for (int q = 0; q < 8; ++q) {
        int d = l5 * 8 + q;
        sd += (double)node[(size_t)row * D_DIM + d] *
              (double)patch[(size_t)pidx * D_DIM + d];
      }
#pragma unroll
      for (int mk = 1; mk <= 16; mk <<= 1) sd += __shfl_xor(sd, mk);
      double d1 = __shfl(sd, 0), d2 = __shfl(sd, 32);
      int win = (d2 > d1) ? i2 : ((d2 == d1) ? (i1 < i2 ? i1 : i2) : i1);
      if (lane == 0) {
        out_hot[(size_t)row * P_DIM + i1] = (win == i1) ? 1.f : 0.f;
        out_hot[(size_t)row * P_DIM + i2] = (win == i2) ? 1.f : 0.f;
      }
    } else {
      // rare: full exact 512-way argmax, rewrite whole row
      double bv = -1e300;
      int bi = 0;
#pragma unroll 1
      for (int pp = 0; pp < 8; ++pp) {
        int p = pp * 64 + lane;
        double sd = 0.0;
        for (int d = 0; d < 256; d += 4) {
          float4 f = *(const float4*)(patch + (size_t)p * D_DIM + d);
          sd += (double)node[(size_t)row * D_DIM + d]     * (double)f.x
              + (double)node[(size_t)row * D_DIM + d + 1] * (double)f.y
              + (double)node[(size_t)row * D_DIM + d + 2] * (double)f.z
              + (double)node[(size_t)row * D_DIM + d + 3] * (double)f.w;
        }
        if (sd > bv) { bv = sd; bi = p; }   // ascending p, strict >
      }
#pragma unroll
      for (int mk = 1; mk < 64; mk <<= 1) {
        double ov = __shfl_xor(bv, mk);
        int oi = __shfl_xor(bi, mk);
        if (ov > bv || (ov == bv && oi < bi)) { bv = ov; bi = oi; }
      }
      int base = lane * 8;
      f32x4 z0, z1;
#pragma unroll
      for (int q = 0; q < 4; ++q) {
        z0[q] = (bi == base + q) ? 1.f : 0.f;
        z1[q] = (bi == base + 4 + q) ? 1.f : 0.f;
      }
      *(f32x4*)(out_hot + (size_t)row * P_DIM + base) = z0;
      *(f32x4*)(out_hot + (size_t)row * P_DIM + base + 4) = z1;
    }
  }
}

extern "C" void kernel_launch(void* const* d_in, const int* in_sizes, int n_in,
                              void* d_out, int out_size, void* d_ws, size_t ws_size,
                              hipStream_t stream) {
  const float* node  = (const float*)d_in[0];
  const float* patch = (const float*)d_in[1];
  float* out_hot = (float*)d_out;
  float* out_rec = out_hot + (size_t)N_ROWS * P_DIM;

  char* ws = (char*)d_ws;
  short* pa_swz   = (short*)ws;                                   // 256 KB
  short* p_T_perm = pa_swz + 131072;                              // 256 KB
  unsigned* suspect = (unsigned*)(ws + 524288);                   // 400 KB
  float* invs       = (float*)(ws + 524288 + 400000);             // 400 KB

  prep_kernel<<<128, 256, 0, stream>>>(patch, pa_swz, p_T_perm);
  gemm1_kernel<<<(N_ROWS + 63) / 64, 256, 0, stream>>>(node, pa_swz,
                                                       (short*)out_rec, out_hot,
                                                       suspect, invs);
  gemm2_kernel<<<(N_ROWS + 63) / 64, 256, 0, stream>>>(p_T_perm, invs, out_rec);
  refine_kernel<<<(N_ROWS + 63) / 64, 64, 0, stream>>>(node, patch, suspect, out_hot);
}

// Round 8
// 363.346 us; speedup vs baseline: 1.6191x; 1.6191x over previous
//
#include <hip/hip_runtime.h>
#include <hip/hip_bf16.h>

#define N_ROWS 100000
#define P_DIM 512
#define D_DIM 256
#define TAU12 2.0e-2f
#define TAU13 1.5e-2f

typedef __attribute__((ext_vector_type(4))) float f32x4;
typedef __attribute__((ext_vector_type(8))) short s16x8;

__device__ __forceinline__ unsigned bf16_rne_bits(float x) {
  unsigned u = __float_as_uint(x);
  return (u + 0x7fffu + ((u >> 16) & 1u)) >> 16;
}

__device__ __forceinline__ void gll16(const void* gsrc, void* ldst) {
  __builtin_amdgcn_global_load_lds(
      (const __attribute__((address_space(1))) unsigned char*)gsrc,
      (__attribute__((address_space(3))) unsigned char*)ldst, 16, 0, 0);
}

// ---------------- prep ----------------
// blocks 0..63:  pa_swz — patch bf16(hi), 8 tiles of [64 p][256 d], rows
//                XOR-swizzled (byte ^= (row&15)<<4): main stages LINEARLY
//                (global_load_lds) and ds_reads are conflict-free.
// blocks 64..127: p_T_perm — patch bf16 transposed [d][p], GEMM2 k-perm
//                baked in; unit u = ((t2*16+kc)*16+cc)*4+g, d = t2*16+cc,
//                elem j <-> p = 32kc + 16*(j>>2) + 4g + (j&3).
__global__ void prep_kernel(const float* __restrict__ patch,
                            short* __restrict__ pa_swz,
                            short* __restrict__ p_T_perm) {
  int b = blockIdx.x, t = threadIdx.x;
  if (b < 64) {
    int u = b * 256 + t;                  // 16384 16B-units total
    int bt = u >> 11;                     // 2048 units per 32KB tile
    int Lb = (u & 2047) * 16;             // dest byte within tile
    int r  = Lb >> 9;                     // p-row in tile (512B rows)
    int srcb = Lb ^ ((r & 15) << 4);      // involutive swizzle
    int p = bt * 64 + r;
    int d0 = (srcb & 511) >> 1;
    s16x8 v;
#pragma unroll
    for (int q = 0; q < 8; ++q)
      v[q] = (short)bf16_rne_bits(patch[(size_t)p * D_DIM + d0 + q]);
    *(s16x8*)(pa_swz + (size_t)u * 8) = v;
  } else {
    int u = (b - 64) * 256 + t;           // 16384 units
    int g = u & 3, cc = (u >> 2) & 15, kc = (u >> 6) & 15, t2 = u >> 10;
    int d = t2 * 16 + cc;
    s16x8 v;
#pragma unroll
    for (int j = 0; j < 8; ++j) {
      int p = 32 * kc + 16 * (j >> 2) + 4 * g + (j & 3);
      v[j] = (short)bf16_rne_bits(patch[(size_t)p * D_DIM + d]);
    }
    *(s16x8*)(p_T_perm + (size_t)u * 8) = v;
  }
}

// stage 16KB chunk T (p-range [32T,32T+32)) into LDS buffer BUF
#define STAGE(BUF, T) do {                                            \
  const char* gs_ = (const char*)pa_swz + (size_t)(T) * 16384         \
                    + (size_t)w * 4096 + (size_t)lane * 16;           \
  char* ls_ = &B1[BUF][w * 4096];                                     \
  _Pragma("unroll")                                                   \
  for (int i_ = 0; i_ < 4; ++i_)                                      \
    gll16(gs_ + i_ * 1024, ls_ + i_ * 1024);                          \
} while (0)

// ---------------- gemm1: logits + softmax + argmax + one-hot + pf ----------
// 4 waves/block, 16 node-rows per wave (as MFMA columns). ROLLED tile loop,
// per-tile finalize: acc = 2 x f32x4 only; ~4KB of code (I$-friendly).
__global__ __launch_bounds__(256, 3)
void gemm1_kernel(const float* __restrict__ node,
                  const short* __restrict__ pa_swz,
                  short* __restrict__ pfout,        // = out_rec region (bf16)
                  float* __restrict__ out_hot,
                  unsigned* __restrict__ suspect,
                  float* __restrict__ invs) {
  __shared__ __align__(16) char B1[2][16384];   // double-buffered 32p tile

  const int tid = threadIdx.x;
  const int lane = tid & 63;
  const int w = tid >> 6;
  const int cc = lane & 15, g = lane >> 4;
  const int G = blockIdx.x * 4 + w;             // 16-row group id
  const int myrow = G * 16 + cc;
  const bool ok = (G * 16) < N_ROWS;

  STAGE(0, 0);                                  // tile-0 staging in flight

  // ---- node B-frags (hi only, nontemporal): elem e <-> k = kk*32+8g+e ----
  s16x8 nhi[8];
  {
    const float* nr = node + (size_t)myrow * D_DIM;
#pragma unroll
    for (int kk = 0; kk < 8; ++kk) {
      f32x4 v0, v1;
      if (ok) {
        v0 = __builtin_nontemporal_load((const f32x4*)(nr + kk * 32 + g * 8));
        v1 = __builtin_nontemporal_load((const f32x4*)(nr + kk * 32 + g * 8 + 4));
      } else {
        v0 = (f32x4){0.f, 0.f, 0.f, 0.f};
        v1 = (f32x4){0.f, 0.f, 0.f, 0.f};
      }
#pragma unroll
      for (int e = 0; e < 4; ++e) {
        nhi[kk][e]     = (short)bf16_rne_bits(v0[e]);
        nhi[kk][e + 4] = (short)bf16_rne_bits(v1[e]);
      }
    }
  }
  __syncthreads();                              // tile 0 staged

  float m1 = -1e30f, m2 = -1e30f, m3 = -1e30f;
  int i1 = 0, i2 = 0;
  float s = 0.f;

  // ds_read byte offsets within a buffer (loop-invariant, 16 values)
  // ad(pt,kk) = ((pt*16+cc)<<9) + (((kk<<6)|(g<<4)) ^ (cc<<4))

#pragma unroll 1
  for (int t = 0; t < 16; ++t) {
    if (t < 15) STAGE((t + 1) & 1, t + 1);
    const char* bp = &B1[t & 1][0];
    f32x4 a0 = (f32x4){0.f, 0.f, 0.f, 0.f};
    f32x4 a1 = (f32x4){0.f, 0.f, 0.f, 0.f};
    __builtin_amdgcn_s_setprio(1);
#pragma unroll
    for (int kk = 0; kk < 8; ++kk) {
      int sw = ((kk << 6) | (g << 4)) ^ (cc << 4);
      s16x8 af0 = *(const s16x8*)(bp + (cc << 9) + sw);
      s16x8 af1 = *(const s16x8*)(bp + ((16 + cc) << 9) + sw);
      a0 = __builtin_amdgcn_mfma_f32_16x16x32_bf16(af0, nhi[kk], a0, 0, 0, 0);
      a1 = __builtin_amdgcn_mfma_f32_16x16x32_bf16(af1, nhi[kk], a1, 0, 0, 0);
    }
    __builtin_amdgcn_s_setprio(0);
    // ---- per-tile finalize: exp + online top-3 + pack + store ----
    {
      s16x8 f;
      int colb = 32 * t + 4 * g;
#pragma unroll
      for (int jj = 0; jj < 4; ++jj) {
        float v = a0[jj];
        int col = colb + jj;
        float e = __expf(v);
        s += e;
        f[jj] = (short)bf16_rne_bits(e);
        bool g1 = v > m1, g2 = v > m2, g3 = v > m3;
        m3 = g2 ? m2 : (g3 ? v : m3);
        i2 = g1 ? i1 : (g2 ? col : i2);
        m2 = g1 ? m1 : (g2 ? v : m2);
        i1 = g1 ? col : i1;
        m1 = g1 ? v : m1;
      }
#pragma unroll
      for (int jj = 0; jj < 4; ++jj) {
        float v = a1[jj];
        int col = colb + 16 + jj;
        float e = __expf(v);
        s += e;
        f[jj + 4] = (short)bf16_rne_bits(e);
        bool g1 = v > m1, g2 = v > m2, g3 = v > m3;
        m3 = g2 ? m2 : (g3 ? v : m3);
        i2 = g1 ? i1 : (g2 ? col : i2);
        m2 = g1 ? m1 : (g2 ? v : m2);
        i1 = g1 ? col : i1;
        m1 = g1 ? v : m1;
      }
      if (ok)
        *(s16x8*)(pfout + ((size_t)G * 1024 + t * 64 + lane) * 8) = f;
    }
    __syncthreads();   // stage done (vmcnt drain) + all reads of buf done
  }

  // ---- merge top-3 across the 4 g-lanes of each row ----
#pragma unroll
  for (int mk = 16; mk <= 32; mk <<= 1) {
    float bm1 = __shfl_xor(m1, mk); int bi1 = __shfl_xor(i1, mk);
    float bm2 = __shfl_xor(m2, mk); int bi2 = __shfl_xor(i2, mk);
    float bm3 = __shfl_xor(m3, mk);
    bool sw = (bm1 > m1) || (bm1 == m1 && bi1 < i1);
    float am1 = sw ? bm1 : m1; int ai1 = sw ? bi1 : i1;
    float am2 = sw ? bm2 : m2; int ai2 = sw ? bi2 : i2;
    float am3 = sw ? bm3 : m3;
    float cm1 = sw ? m1 : bm1; int ci1 = sw ? i1 : bi1;
    float cm2 = sw ? m2 : bm2;
    bool t2b = (cm1 > am2) || (cm1 == am2 && ci1 < ai2);
    m1 = am1; i1 = ai1;
    m2 = t2b ? cm1 : am2; i2 = t2b ? ci1 : ai2;
    m3 = t2b ? fmaxf(am2, cm2) : fmaxf(am3, cm1);
  }
  s += __shfl_xor(s, 16);
  s += __shfl_xor(s, 32);

  if (g == 0 && ok) {
    invs[myrow] = 1.0f / s;
    unsigned codev = 0u;
    if (m1 - m2 < TAU12)
      codev = 0x80000000u | ((m1 - m3 < TAU13) ? 0x40000000u : 0u)
            | ((unsigned)i2 << 9) | (unsigned)i1;
    suspect[myrow] = codev;
  }

  // ---- one-hot write (rolled; 4 g-lanes cover 64B per row) ----
  if (ok) {
    float* orow = out_hot + (size_t)myrow * P_DIM;
#pragma unroll 1
    for (int c2i = 0; c2i < 32; ++c2i) {
      int col = c2i * 16 + g * 4;
      f32x4 z;
      z[0] = (i1 == col + 0) ? 1.f : 0.f;
      z[1] = (i1 == col + 1) ? 1.f : 0.f;
      z[2] = (i1 == col + 2) ? 1.f : 0.f;
      z[3] = (i1 == col + 3) ? 1.f : 0.f;
      __builtin_nontemporal_store(z, (f32x4*)(orow + col));
    }
  }
}

// ---------------- gemm2: out_rec = probs @ patch ----------------------------
// Reads pf (bf16, unnormalized) from the out_rec region and overwrites the
// SAME per-group 16KB region with f32 results (race-free: one block owns it).
__global__ __launch_bounds__(256, 2)
void gemm2_kernel(const short* __restrict__ p_T_perm,
                  const float* __restrict__ invs,
                  float* __restrict__ rec) {
  const int tid = threadIdx.x;
  const int lane = tid & 63;
  const int w = tid >> 6;
  const int cc = lane & 15, g = lane >> 4;
  const int G = blockIdx.x * 4 + w;
  if (G * 16 >= N_ROWS) return;                 // wave-uniform, no barriers
  const int myrow = G * 16 + cc;
  const float inv = invs[myrow];

  const s16x8* pf8 = (const s16x8*)rec;         // alias: pf lives here
  s16x8 pfA[8], pfB[8];
#pragma unroll
  for (int kc = 0; kc < 8; ++kc)
    pfA[kc] = pf8[(size_t)G * 1024 + kc * 64 + lane];
#pragma unroll
  for (int kc = 0; kc < 8; ++kc)
    pfB[kc] = pf8[(size_t)G * 1024 + 512 + kc * 64 + lane];

  const s16x8* pT = (const s16x8*)p_T_perm;
  const int lidx = (cc << 2) + g;
#pragma unroll 1
  for (int t2 = 0; t2 < 16; ++t2) {
    s16x8 aH[16];
    const int ub = t2 << 10;
#pragma unroll
    for (int kc = 0; kc < 16; ++kc) aH[kc] = pT[ub + (kc << 6) + lidx];
    f32x4 c2 = (f32x4){0.f, 0.f, 0.f, 0.f};
    __builtin_amdgcn_s_setprio(1);
#pragma unroll
    for (int kc = 0; kc < 8; ++kc)
      c2 = __builtin_amdgcn_mfma_f32_16x16x32_bf16(aH[kc], pfA[kc], c2, 0, 0, 0);
#pragma unroll
    for (int kc = 0; kc < 8; ++kc)
      c2 = __builtin_amdgcn_mfma_f32_16x16x32_bf16(aH[kc + 8], pfB[kc], c2, 0, 0, 0);
    __builtin_amdgcn_s_setprio(0);
    c2[0] *= inv; c2[1] *= inv; c2[2] *= inv; c2[3] *= inv;
    __builtin_nontemporal_store(c2, (f32x4*)(rec + (size_t)myrow * D_DIM + 16 * t2 + 4 * g));
  }
}

// ---------------- refine: fp64 check of the 2 candidates (dense scan) ------
__global__ void refine_kernel(const float* __restrict__ node,
                              const float* __restrict__ patch,
                              const unsigned* __restrict__ suspect,
                              float* __restrict__ out_hot) {
  const int lane = threadIdx.x;            // blockDim.x == 64
  const int r0 = blockIdx.x * 64;
  unsigned code = (r0 + lane < N_ROWS) ? suspect[r0 + lane] : 0u;
  unsigned long long mask = __ballot(code != 0u);
  while (mask) {
    int src = __ffsll((long long)mask) - 1;
    mask &= mask - 1;
    unsigned c = __shfl(code, src);
    int row = r0 + src;
    int i1 = (int)(c & 511u), i2 = (int)((c >> 9) & 511u);
    if (!(c & 0x40000000u)) {
      // exact fp64 dots for the two candidates; halves of the wave split them
      int pidx = (lane >= 32) ? i2 : i1;
      int l5 = lane & 31;
      double sd = 0.0;
#pragma unroll
      for (int q = 0; q < 8; ++q) {
        int d = l5 * 8 + q;
        sd += (double)node[(size_t)row * D_DIM + d] *
              (double)patch[(size_t)pidx * D_DIM + d];
      }
#pragma unroll
      for (int mk = 1; mk <= 16; mk <<= 1) sd += __shfl_xor(sd, mk);
      double d1 = __shfl(sd, 0), d2 = __shfl(sd, 32);
      int win = (d2 > d1) ? i2 : ((d2 == d1) ? (i1 < i2 ? i1 : i2) : i1);
      if (lane == 0) {
        out_hot[(size_t)row * P_DIM + i1] = (win == i1) ? 1.f : 0.f;
        out_hot[(size_t)row * P_DIM + i2] = (win == i2) ? 1.f : 0.f;
      }
    } else {
      // rare: full exact 512-way argmax, rewrite whole row
      double bv = -1e300;
      int bi = 0;
#pragma unroll 1
      for (int pp = 0; pp < 8; ++pp) {
        int p = pp * 64 + lane;
        double sd = 0.0;
        for (int d = 0; d < 256; d += 4) {
          float4 f = *(const float4*)(patch + (size_t)p * D_DIM + d);
          sd += (double)node[(size_t)row * D_DIM + d]     * (double)f.x
              + (double)node[(size_t)row * D_DIM + d + 1] * (double)f.y
              + (double)node[(size_t)row * D_DIM + d + 2] * (double)f.z
              + (double)node[(size_t)row * D_DIM + d + 3] * (double)f.w;
        }
        if (sd > bv) { bv = sd; bi = p; }   // ascending p, strict >
      }
#pragma unroll
      for (int mk = 1; mk < 64; mk <<= 1) {
        double ov = __shfl_xor(bv, mk);
        int oi = __shfl_xor(bi, mk);
        if (ov > bv || (ov == bv && oi < bi)) { bv = ov; bi = oi; }
      }
      int base = lane * 8;
      f32x4 z0, z1;
#pragma unroll
      for (int q = 0; q < 4; ++q) {
        z0[q] = (bi == base + q) ? 1.f : 0.f;
        z1[q] = (bi == base + 4 + q) ? 1.f : 0.f;
      }
      *(f32x4*)(out_hot + (size_t)row * P_DIM + base) = z0;
      *(f32x4*)(out_hot + (size_t)row * P_DIM + base + 4) = z1;
    }
  }
}

extern "C" void kernel_launch(void* const* d_in, const int* in_sizes, int n_in,
                              void* d_out, int out_size, void* d_ws, size_t ws_size,
                              hipStream_t stream) {
  const float* node  = (const float*)d_in[0];
  const float* patch = (const float*)d_in[1];
  float* out_hot = (float*)d_out;
  float* out_rec = out_hot + (size_t)N_ROWS * P_DIM;

  char* ws = (char*)d_ws;
  short* pa_swz   = (short*)ws;                                   // 256 KB
  short* p_T_perm = pa_swz + 131072;                              // 256 KB
  unsigned* suspect = (unsigned*)(ws + 524288);                   // 400 KB
  float* invs       = (float*)(ws + 524288 + 400000);             // 400 KB

  prep_kernel<<<128, 256, 0, stream>>>(patch, pa_swz, p_T_perm);
  gemm1_kernel<<<(N_ROWS + 63) / 64, 256, 0, stream>>>(node, pa_swz,
                                                       (short*)out_rec, out_hot,
                                                       suspect, invs);
  gemm2_kernel<<<(N_ROWS + 63) / 64, 256, 0, stream>>>(p_T_perm, invs, out_rec);
  refine_kernel<<<(N_ROWS + 63) / 64, 64, 0, stream>>>(node, patch, suspect, out_hot);
}